// Round 7
// baseline (162.455 us; speedup 1.0000x reference)
//
#include <hip/hip_runtime.h>
#include <hip/hip_fp16.h>

#define N_NODES 50000
#define N_EDGES 800000
#define N_GRAPHS 256
#define D_FEAT 96
#define HIDDEN 32

#define NB 196        // bins: bin = dst >> 8 (256 nodes/bin), 49999>>8 = 195
#define PB 400        // partition blocks
#define PCHUNK 2000   // 400 * 2000 = 800000 exactly
#define SEGCAP 48     // per-(block,bin) segment capacity; mean 10.2, 11+ sigma
#define GWIN 16       // pooled-graph LDS window per 256-node bin
#define LCAP 6144     // per-bin LDS edge-list capacity (mean 4082, 32 sigma)

// ---------------------------------------------------------------------------
// Kernel A: blocks 0..PB-1: single-pass edge partition into deterministic
// per-(block,bin) segments (no global cursor, no pre-zeroed state).
// Blocks PB..: y16 = fp16(x @ W1), plus zero-init of sums/counts.
__global__ void __launch_bounds__(256)
k_front(const float* __restrict__ x, const float* __restrict__ W1,
        __half* __restrict__ y16,
        const int* __restrict__ src, const int* __restrict__ dst,
        unsigned int* __restrict__ binned, unsigned short* __restrict__ cnt,
        float* __restrict__ sums, float* __restrict__ counts) {
    int blk = blockIdx.x;
    int tid = threadIdx.x;
    if (blk < PB) {
        __shared__ int hcur[NB];
        for (int i = tid; i < NB; i += 256) hcur[i] = 0;
        __syncthreads();

        int e0 = blk * PCHUNK, e1 = e0 + PCHUNK;
        for (int e = e0 + tid; e < e1; e += 256) {   // independent iterations -> ILP
            int sn = src[e];
            int d  = dst[e];
            int b  = d >> 8;
            int pos = atomicAdd(&hcur[b], 1);
            if (pos < SEGCAP)                         // statistically never taken
                binned[(size_t)(b * PB + blk) * SEGCAP + pos] =
                    (unsigned)sn | ((unsigned)(d & 255) << 16);
        }
        __syncthreads();

        for (int i = tid; i < NB; i += 256) {
            int c = hcur[i]; if (c > SEGCAP) c = SEGCAP;
            cnt[i * PB + blk] = (unsigned short)c;
        }
    } else {
        int gid = (blk - PB) * 256 + tid;             // 0 .. N_NODES*HIDDEN-1
        if (gid < N_GRAPHS * HIDDEN) sums[gid] = 0.f; // fold init in (runs before k_agg)
        if (gid < N_GRAPHS) counts[gid] = 0.f;
        int node = gid >> 5;
        int f = gid & 31;
        const float4* xr4 = (const float4*)(x + (size_t)node * D_FEAT);
        float acc = 0.f;
#pragma unroll
        for (int k4 = 0; k4 < D_FEAT / 4; ++k4) {
            float4 xv = xr4[k4];
            acc = fmaf(xv.x, W1[(k4 * 4 + 0) * HIDDEN + f], acc);
            acc = fmaf(xv.y, W1[(k4 * 4 + 1) * HIDDEN + f], acc);
            acc = fmaf(xv.z, W1[(k4 * 4 + 2) * HIDDEN + f], acc);
            acc = fmaf(xv.w, W1[(k4 * 4 + 3) * HIDDEN + f], acc);
        }
        y16[gid] = __float2half(acc);
    }
}

// ---------------------------------------------------------------------------
// Kernel B: per-bin: scan segment counts -> pack to LDS -> counting-sort to
// per-node CSR -> register gather (fp16 y, fp32 acc) -> MLP -> windowed pool.
__global__ void __launch_bounds__(1024)
k_agg(const unsigned int* __restrict__ binned, const unsigned short* __restrict__ cnt,
      const __half* __restrict__ y16, const int* __restrict__ batch,
      const float* __restrict__ b1, const float* __restrict__ W2,
      const float* __restrict__ b2,
      float* __restrict__ sums, float* __restrict__ counts) {
    __shared__ unsigned int list[LCAP];        // 24 KB packed (src|dstlo<<16)
    __shared__ unsigned short list2[LCAP];     // 12 KB node-sorted src
    __shared__ unsigned int sA[512], sB[512];  // 4 KB scan ping-pong
    __shared__ unsigned int ncnt[256];
    __shared__ unsigned int offs[257];
    __shared__ unsigned int cur[256];
    __shared__ float w2s[HIDDEN * HIDDEN];     // 4 KB
    __shared__ float accs[GWIN * HIDDEN];      // 2 KB
    __shared__ float cntsl[GWIN];

    int tid = threadIdx.x;
    int bin = blockIdx.x;
    if (tid < 256) ncnt[tid] = 0;
    for (int i = tid; i < HIDDEN * HIDDEN; i += 1024) w2s[i] = W2[i];
    if (tid < GWIN * HIDDEN) accs[tid] = 0.f;
    if (tid < GWIN) cntsl[tid] = 0.f;
    // scan input: per-segment counts for this bin
    if (tid < 512) sA[tid] = (tid < PB) ? (unsigned)cnt[bin * PB + tid] : 0u;
    __syncthreads();

    // inclusive Hillis-Steele scan over 512 (9 steps, ping-pong) -> ends in sB
    unsigned int* ps = sA; unsigned int* pd = sB;
    for (int d = 1; d < 512; d <<= 1) {
        if (tid < 512) {
            unsigned v = ps[tid];
            if (tid >= d) v += ps[tid - d];
            pd[tid] = v;
        }
        __syncthreads();
        unsigned int* t = ps; ps = pd; pd = t;
    }
    // ps holds inclusive scan. exclusive offset(t) = t ? ps[t-1] : 0
    int ecount = (int)ps[PB - 1];
    if (ecount > LCAP) ecount = LCAP;

    // pack segments into contiguous LDS list (400 parallel copiers)
    if (tid < PB) {
        int c = (int)((tid < PB) ? (ps[tid] - (tid ? ps[tid - 1] : 0u)) : 0u);
        int o = (int)(tid ? ps[tid - 1] : 0u);
        const unsigned int* seg = binned + (size_t)(bin * PB + tid) * SEGCAP;
        for (int i = 0; i < c; ++i)
            if (o + i < LCAP) list[o + i] = seg[i];
    }
    __syncthreads();

    // per-node histogram
    for (int e = tid; e < ecount; e += 1024)
        atomicAdd(&ncnt[list[e] >> 16], 1u);
    __syncthreads();

    // exclusive scan over 256 node counts (reuse ping-pong arrays)
    if (tid < 256) sA[tid] = ncnt[tid];
    __syncthreads();
    ps = sA; pd = sB;
    for (int d = 1; d < 256; d <<= 1) {
        if (tid < 256) {
            unsigned v = ps[tid];
            if (tid >= d) v += ps[tid - d];
            pd[tid] = v;
        }
        __syncthreads();
        unsigned int* t = ps; ps = pd; pd = t;
    }
    if (tid < 256) {
        offs[tid + 1] = ps[tid];
        cur[tid] = tid ? ps[tid - 1] : 0u;
    }
    if (tid == 0) offs[0] = 0;
    __syncthreads();

    // place src ids into node-sorted list2
    for (int e = tid; e < ecount; e += 1024) {
        unsigned p = list[e];
        unsigned pos = atomicAdd(&cur[p >> 16], 1u);
        list2[pos] = (unsigned short)(p & 0xFFFFu);
    }
    __syncthreads();

    int node0 = bin << 8;
    int nn = N_NODES - node0; if (nn > 256) nn = 256;
    int g = tid >> 5;      // group 0..31 (two groups per wave64)
    int f = tid & 31;      // feature lane
    int gfirst = batch[node0];

    for (int ln = g * 8; ln < g * 8 + 8; ++ln) {
        if (ln >= nn) break;
        int node = node0 + ln;
        float acc = __half2float(y16[(size_t)node * HIDDEN + f]);   // self term
        int j = offs[ln], jend = offs[ln + 1];
        for (; j + 8 <= jend; j += 8) {               // 8 y-rows in flight
            unsigned s0 = list2[j],     s1 = list2[j + 1], s2 = list2[j + 2], s3 = list2[j + 3];
            unsigned s4 = list2[j + 4], s5 = list2[j + 5], s6 = list2[j + 6], s7 = list2[j + 7];
            float a0 = __half2float(y16[(size_t)s0 * HIDDEN + f]);
            float a1 = __half2float(y16[(size_t)s1 * HIDDEN + f]);
            float a2 = __half2float(y16[(size_t)s2 * HIDDEN + f]);
            float a3 = __half2float(y16[(size_t)s3 * HIDDEN + f]);
            float a4 = __half2float(y16[(size_t)s4 * HIDDEN + f]);
            float a5 = __half2float(y16[(size_t)s5 * HIDDEN + f]);
            float a6 = __half2float(y16[(size_t)s6 * HIDDEN + f]);
            float a7 = __half2float(y16[(size_t)s7 * HIDDEN + f]);
            acc += ((a0 + a1) + (a2 + a3)) + ((a4 + a5) + (a6 + a7));
        }
        for (; j < jend; ++j)
            acc += __half2float(y16[(size_t)list2[j] * HIDDEN + f]);

        float h1 = fmaxf(acc + b1[f], 0.f);
        float h2 = b2[f];
#pragma unroll
        for (int k = 0; k < HIDDEN; ++k)              // h1[k] via intra-group shuffle
            h2 = fmaf(__shfl(h1, k, 32), w2s[k * HIDDEN + f], h2);
        float h = fmaxf(h2, 0.f);

        int gr = batch[node];
        int b = gr - gfirst;
        if (b < GWIN) {
            atomicAdd(&accs[b * HIDDEN + f], h);
            if (f == 0) atomicAdd(&cntsl[b], 1.f);
        } else {
            atomicAdd(&sums[(size_t)gr * HIDDEN + f], h);
            if (f == 0) atomicAdd(&counts[gr], 1.f);
        }
    }
    __syncthreads();

    for (int i = tid; i < GWIN * HIDDEN; i += 1024) {
        float v = accs[i];
        if (v != 0.f) atomicAdd(&sums[(size_t)gfirst * HIDDEN + i], v);
    }
    if (tid < GWIN) {
        float c = cntsl[tid];
        if (c != 0.f) atomicAdd(&counts[gfirst + tid], c);
    }
}

// ---------------------------------------------------------------------------
// Kernel C: out[g] = (sums[g]/max(counts[g],1)) @ Wc + bc
__global__ void k_out(const float* __restrict__ sums, const float* __restrict__ counts,
                      const float* __restrict__ Wc, const float* __restrict__ bc,
                      float* __restrict__ out) {
    int g = threadIdx.x;
    if (g >= N_GRAPHS) return;
    float inv = 1.f / fmaxf(counts[g], 1.f);
    float o0 = bc[0], o1 = bc[1];
#pragma unroll
    for (int k = 0; k < HIDDEN; ++k) {
        float p = sums[(size_t)g * HIDDEN + k] * inv;
        o0 = fmaf(p, Wc[k * 2 + 0], o0);
        o1 = fmaf(p, Wc[k * 2 + 1], o1);
    }
    out[g * 2 + 0] = o0;
    out[g * 2 + 1] = o1;
}

// ---------------------------------------------------------------------------
extern "C" void kernel_launch(void* const* d_in, const int* in_sizes, int n_in,
                              void* d_out, int out_size, void* d_ws, size_t ws_size,
                              hipStream_t stream) {
    const float* x     = (const float*)d_in[0];
    const int*   ei    = (const int*)d_in[1];   // [2, N_EDGES]: src row then dst row
    const int*   batch = (const int*)d_in[2];
    const float* W1    = (const float*)d_in[3];
    const float* b1    = (const float*)d_in[4];
    const float* W2    = (const float*)d_in[5];
    const float* b2    = (const float*)d_in[6];
    const float* Wc    = (const float*)d_in[7];
    const float* bc    = (const float*)d_in[8];
    float* out = (float*)d_out;

    // Workspace layout (byte offsets):
    //   0         sums    8192 f              (32768 B)
    //   32768     counts  256 f               (1024 B)
    //   33792     cnt     NB*PB u16           (156800 B)
    //   190592    binned  NB*PB*SEGCAP u32    (15052800 B)
    //   15243392  y16     1.6M half           (3200000 B)   -> total ~18.4 MB
    char* ws = (char*)d_ws;
    float*          sums   = (float*)ws;
    float*          counts = (float*)(ws + 32768);
    unsigned short* cnt    = (unsigned short*)(ws + 33792);
    unsigned int*   binned = (unsigned int*)(ws + 190592);
    __half*         y16    = (__half*)(ws + 15243392);

    k_front<<<PB + N_NODES * HIDDEN / 256, 256, 0, stream>>>(
        x, W1, y16, ei, ei + N_EDGES, binned, cnt, sums, counts);

    k_agg<<<NB, 1024, 0, stream>>>(binned, cnt, y16, batch,
                                   b1, W2, b2, sums, counts);

    k_out<<<1, 256, 0, stream>>>(sums, counts, Wc, bc, out);
}

// Round 8
// 133.640 us; speedup vs baseline: 1.2156x; 1.2156x over previous
//
#include <hip/hip_runtime.h>
#include <hip/hip_fp16.h>

#define N_NODES 50000
#define N_EDGES 800000
#define N_GRAPHS 256
#define D_FEAT 96
#define HIDDEN 32

#define NB 196        // bins: bin = dst >> 8 (256 nodes/bin)
#define PB 400        // partition blocks
#define PCHUNK 2000   // 400 * 2000 = 800000 exactly
#define SEGCAP 64     // per-(block,bin) segment capacity (pow2 for coalesced pack)
#define GWIN 16       // pooled-graph LDS window per 256-node bin
#define LCAP 6400     // per-bin LDS edge-list capacity (padded mean ~5890, 8 sigma)
#define XT 64         // nodes per xw1 tile block
#define XBLK 782      // ceil(50000/64)
#define XS_STRIDE 97  // padded LDS row stride (conflict-free lane=node reads)
#define DUMMY_NODE N_NODES   // extra zeroed y16 row for list padding

// ---------------------------------------------------------------------------
// Kernel A: blocks 0..PB-1 partition edges into per-(block,bin) segments;
// blocks PB.. compute y16 = fp16(x @ W1) via LDS-staged tiles (VALU-bound).
__global__ void __launch_bounds__(256)
k_front(const float* __restrict__ x, const float* __restrict__ W1,
        __half* __restrict__ y16,
        const int* __restrict__ src, const int* __restrict__ dst,
        unsigned int* __restrict__ binned, unsigned short* __restrict__ cnt,
        float* __restrict__ sums, float* __restrict__ counts) {
    int blk = blockIdx.x;
    int tid = threadIdx.x;
    if (blk < PB) {
        __shared__ int hcur[NB];
        for (int i = tid; i < NB; i += 256) hcur[i] = 0;
        __syncthreads();

        int e0 = blk * PCHUNK, e1 = e0 + PCHUNK;
        for (int e = e0 + tid; e < e1; e += 256) {
            int sn = src[e];
            int d  = dst[e];
            int b  = d >> 8;
            int pos = atomicAdd(&hcur[b], 1);
            if (pos < SEGCAP)                       // statistically never taken
                binned[((size_t)b * PB + blk) * SEGCAP + pos] =
                    (unsigned)sn | ((unsigned)(d & 255) << 16);
        }
        __syncthreads();

        for (int i = tid; i < NB; i += 256) {
            int c = hcur[i]; if (c > SEGCAP) c = SEGCAP;
            cnt[i * PB + blk] = (unsigned short)c;
        }
    } else {
        __shared__ float xs[XT * XS_STRIDE];        // 24.8 KB
        int xb = blk - PB;
        int n0 = xb * XT;
        int nn = N_NODES - n0; if (nn > XT) nn = XT;

        // folded init chores (these blocks run before k_agg)
        int gid = xb * 256 + tid;
        if (gid < N_GRAPHS * HIDDEN) sums[gid] = 0.f;
        if (gid < N_GRAPHS) counts[gid] = 0.f;
        if (xb == 0 && tid < HIDDEN)
            y16[(size_t)DUMMY_NODE * HIDDEN + tid] = __float2half(0.f);

        // stage x tile: nn rows, coalesced float4 stream
        const float4* xsrc = (const float4*)(x + (size_t)n0 * D_FEAT);
        int nf4 = nn * (D_FEAT / 4);                // up to 1536
        for (int idx = tid; idx < nf4; idx += 256) {
            int ln = (idx * 2731) >> 16;            // idx / 24 for idx < 1536
            int k4 = idx - ln * 24;
            float4 v = xsrc[idx];
            float* dp = &xs[ln * XS_STRIDE + k4 * 4];
            dp[0] = v.x; dp[1] = v.y; dp[2] = v.z; dp[3] = v.w;
        }
        __syncthreads();

        int lane = tid & 63;                        // node within tile
        int f0 = (tid >> 6) << 3;                   // wave-uniform feature base
        f0 = __builtin_amdgcn_readfirstlane(f0);    // force SGPR

        if (lane < nn) {
            const float* xr = &xs[lane * XS_STRIDE];
            const float4* W1v = (const float4*)W1;  // row k = 8 float4s
            float acc[8];
#pragma unroll
            for (int j = 0; j < 8; ++j) acc[j] = 0.f;
#pragma unroll
            for (int k = 0; k < D_FEAT; ++k) {
                float xv = xr[k];                   // LDS, conflict-free (stride 97)
                float4 wa = W1v[k * 8 + (f0 >> 2)];     // uniform addr
                float4 wb = W1v[k * 8 + (f0 >> 2) + 1];
                acc[0] = fmaf(xv, wa.x, acc[0]);
                acc[1] = fmaf(xv, wa.y, acc[1]);
                acc[2] = fmaf(xv, wa.z, acc[2]);
                acc[3] = fmaf(xv, wa.w, acc[3]);
                acc[4] = fmaf(xv, wb.x, acc[4]);
                acc[5] = fmaf(xv, wb.y, acc[5]);
                acc[6] = fmaf(xv, wb.z, acc[6]);
                acc[7] = fmaf(xv, wb.w, acc[7]);
            }
            __half2 h01 = __floats2half2_rn(acc[0], acc[1]);
            __half2 h23 = __floats2half2_rn(acc[2], acc[3]);
            __half2 h45 = __floats2half2_rn(acc[4], acc[5]);
            __half2 h67 = __floats2half2_rn(acc[6], acc[7]);
            float4 pack;
            pack.x = __uint_as_float(*(const unsigned*)&h01);
            pack.y = __uint_as_float(*(const unsigned*)&h23);
            pack.z = __uint_as_float(*(const unsigned*)&h45);
            pack.w = __uint_as_float(*(const unsigned*)&h67);
            *(float4*)&y16[(size_t)(n0 + lane) * HIDDEN + f0] = pack;  // 16B/lane
        }
    }
}

// ---------------------------------------------------------------------------
// Kernel B: per-bin: scan seg counts -> COALESCED pack -> counting-sort with
// 8-padded per-node lists -> pure-pipelined register gather -> MLP -> pool.
__global__ void __launch_bounds__(1024)
k_agg(const unsigned int* __restrict__ binned, const unsigned short* __restrict__ cnt,
      const __half* __restrict__ y16, const int* __restrict__ batch,
      const float* __restrict__ b1, const float* __restrict__ W2,
      const float* __restrict__ b2,
      float* __restrict__ sums, float* __restrict__ counts) {
    __shared__ unsigned int list[LCAP];        // 25.6 KB packed (src|dstlo<<16)
    __shared__ unsigned short list2[LCAP];     // 12.8 KB node-sorted src (8-padded)
    __shared__ unsigned int sA[512], sB[512];  // 4 KB scan ping-pong
    __shared__ unsigned short cs[PB];
    __shared__ unsigned int sOfs[PB];
    __shared__ unsigned int ncnt[256];
    __shared__ unsigned int offs[257];
    __shared__ unsigned int cur[256];
    __shared__ float w2s[HIDDEN * HIDDEN];     // 4 KB
    __shared__ float accs[GWIN * HIDDEN];      // 2 KB
    __shared__ float cntsl[GWIN];

    int tid = threadIdx.x;
    int bin = blockIdx.x;
    if (tid < 256) ncnt[tid] = 0;
    for (int i = tid; i < HIDDEN * HIDDEN; i += 1024) w2s[i] = W2[i];
    if (tid < GWIN * HIDDEN) accs[tid] = 0.f;
    if (tid < GWIN) cntsl[tid] = 0.f;
    if (tid < 512) {
        unsigned c = (tid < PB) ? (unsigned)cnt[bin * PB + tid] : 0u;
        if (tid < PB) cs[tid] = (unsigned short)c;
        sA[tid] = c;
    }
    __syncthreads();

    // inclusive scan over 512 (9 steps)
    unsigned *ps = sA, *pd = sB;
    for (int d = 1; d < 512; d <<= 1) {
        if (tid < 512) { unsigned v = ps[tid]; if (tid >= d) v += ps[tid - d]; pd[tid] = v; }
        __syncthreads();
        unsigned* t = ps; ps = pd; pd = t;
    }
    if (tid < PB) sOfs[tid] = tid ? ps[tid - 1] : 0u;
    int ecount = (int)ps[PB - 1];
    if (ecount > LCAP) ecount = LCAP;
    __syncthreads();

    // COALESCED pack: stream the bin's whole segment region stride-1
    const unsigned int* ebase = binned + (size_t)bin * PB * SEGCAP;
    for (int idx = tid; idx < PB * SEGCAP; idx += 1024) {
        int s = idx >> 6;                          // SEGCAP = 64
        int i = idx & 63;
        if (i < (int)cs[s]) {
            unsigned pos = sOfs[s] + i;
            if (pos < LCAP) list[pos] = ebase[idx];
        }
    }
    __syncthreads();

    // per-node histogram
    for (int e = tid; e < ecount; e += 1024)
        atomicAdd(&ncnt[list[e] >> 16], 1u);
    __syncthreads();

    // exclusive scan over 8-PADDED node counts
    if (tid < 256) sA[tid] = (ncnt[tid] + 7u) & ~7u;
    __syncthreads();
    ps = sA; pd = sB;
    for (int d = 1; d < 256; d <<= 1) {
        if (tid < 256) { unsigned v = ps[tid]; if (tid >= d) v += ps[tid - d]; pd[tid] = v; }
        __syncthreads();
        unsigned* t = ps; ps = pd; pd = t;
    }
    if (tid < 256) {
        offs[tid + 1] = ps[tid];
        cur[tid] = tid ? ps[tid - 1] : 0u;
    }
    if (tid == 0) offs[0] = 0;
    __syncthreads();

    // place src ids
    for (int e = tid; e < ecount; e += 1024) {
        unsigned p = list[e];
        unsigned pos = atomicAdd(&cur[p >> 16], 1u);
        if (pos < LCAP) list2[pos] = (unsigned short)(p & 0xFFFFu);
    }
    __syncthreads();
    // pad each node's list to its 8-multiple with the dummy (zero) row
    if (tid < 256) {
        unsigned i0 = cur[tid], i1 = offs[tid + 1];
        for (unsigned i = i0; i < i1 && i < LCAP; ++i)
            list2[i] = (unsigned short)DUMMY_NODE;
    }
    __syncthreads();

    int node0 = bin << 8;
    int nn = N_NODES - node0; if (nn > 256) nn = 256;
    int g = tid >> 5;      // group 0..31 (two per wave64)
    int f = tid & 31;      // feature lane
    int gfirst = batch[node0];

    for (int ln = g * 8; ln < g * 8 + 8; ++ln) {
        if (ln >= nn) break;
        int node = node0 + ln;
        float acc = __half2float(y16[(size_t)node * HIDDEN + f]);   // self term
        int j = offs[ln], jend = offs[ln + 1];                      // both %8 == 0
        for (; j < jend; j += 8) {                 // pure 8-deep pipeline
            ushort4 qa = *(const ushort4*)&list2[j];
            ushort4 qb = *(const ushort4*)&list2[j + 4];
            float a0 = __half2float(y16[(size_t)qa.x * HIDDEN + f]);
            float a1 = __half2float(y16[(size_t)qa.y * HIDDEN + f]);
            float a2 = __half2float(y16[(size_t)qa.z * HIDDEN + f]);
            float a3 = __half2float(y16[(size_t)qa.w * HIDDEN + f]);
            float a4 = __half2float(y16[(size_t)qb.x * HIDDEN + f]);
            float a5 = __half2float(y16[(size_t)qb.y * HIDDEN + f]);
            float a6 = __half2float(y16[(size_t)qb.z * HIDDEN + f]);
            float a7 = __half2float(y16[(size_t)qb.w * HIDDEN + f]);
            acc += ((a0 + a1) + (a2 + a3)) + ((a4 + a5) + (a6 + a7));
        }

        float h1 = fmaxf(acc + b1[f], 0.f);
        float h2 = b2[f];
#pragma unroll
        for (int k = 0; k < HIDDEN; ++k)           // h1[k] via intra-group shuffle
            h2 = fmaf(__shfl(h1, k, 32), w2s[k * HIDDEN + f], h2);
        float h = fmaxf(h2, 0.f);

        int gr = batch[node];
        int b = gr - gfirst;
        if (b < GWIN) {
            atomicAdd(&accs[b * HIDDEN + f], h);
            if (f == 0) atomicAdd(&cntsl[b], 1.f);
        } else {
            atomicAdd(&sums[(size_t)gr * HIDDEN + f], h);
            if (f == 0) atomicAdd(&counts[gr], 1.f);
        }
    }
    __syncthreads();

    for (int i = tid; i < GWIN * HIDDEN; i += 1024) {
        float v = accs[i];
        if (v != 0.f) atomicAdd(&sums[(size_t)gfirst * HIDDEN + i], v);
    }
    if (tid < GWIN) {
        float c = cntsl[tid];
        if (c != 0.f) atomicAdd(&counts[gfirst + tid], c);
    }
}

// ---------------------------------------------------------------------------
// Kernel C: out[g] = (sums[g]/max(counts[g],1)) @ Wc + bc
__global__ void k_out(const float* __restrict__ sums, const float* __restrict__ counts,
                      const float* __restrict__ Wc, const float* __restrict__ bc,
                      float* __restrict__ out) {
    int g = threadIdx.x;
    if (g >= N_GRAPHS) return;
    float inv = 1.f / fmaxf(counts[g], 1.f);
    float o0 = bc[0], o1 = bc[1];
#pragma unroll
    for (int k = 0; k < HIDDEN; ++k) {
        float p = sums[(size_t)g * HIDDEN + k] * inv;
        o0 = fmaf(p, Wc[k * 2 + 0], o0);
        o1 = fmaf(p, Wc[k * 2 + 1], o1);
    }
    out[g * 2 + 0] = o0;
    out[g * 2 + 1] = o1;
}

// ---------------------------------------------------------------------------
extern "C" void kernel_launch(void* const* d_in, const int* in_sizes, int n_in,
                              void* d_out, int out_size, void* d_ws, size_t ws_size,
                              hipStream_t stream) {
    const float* x     = (const float*)d_in[0];
    const int*   ei    = (const int*)d_in[1];   // [2, N_EDGES]: src row then dst row
    const int*   batch = (const int*)d_in[2];
    const float* W1    = (const float*)d_in[3];
    const float* b1    = (const float*)d_in[4];
    const float* W2    = (const float*)d_in[5];
    const float* b2    = (const float*)d_in[6];
    const float* Wc    = (const float*)d_in[7];
    const float* bc    = (const float*)d_in[8];
    float* out = (float*)d_out;

    // Workspace layout (byte offsets):
    //   0         sums    8192 f                 (32768 B)
    //   32768     counts  256 f                  (1024 B)
    //   33792     cnt     NB*PB u16              (156800 B)
    //   190592    binned  NB*PB*SEGCAP u32       (20070400 B)
    //   20260992  y16     (N_NODES+1)*32 half    (3200064 B)   total ~23.5 MB
    char* ws = (char*)d_ws;
    float*          sums   = (float*)ws;
    float*          counts = (float*)(ws + 32768);
    unsigned short* cnt    = (unsigned short*)(ws + 33792);
    unsigned int*   binned = (unsigned int*)(ws + 190592);
    __half*         y16    = (__half*)(ws + 20260992);

    k_front<<<PB + XBLK, 256, 0, stream>>>(
        x, W1, y16, ei, ei + N_EDGES, binned, cnt, sums, counts);

    k_agg<<<NB, 1024, 0, stream>>>(binned, cnt, y16, batch,
                                   b1, W2, b2, sums, counts);

    k_out<<<1, 256, 0, stream>>>(sums, counts, Wc, bc, out);
}